// Round 1
// baseline (243.874 us; speedup 1.0000x reference)
//
#include <hip/hip_runtime.h>
#include <math.h>

#ifndef M_PI
#define M_PI 3.14159265358979323846
#endif

#define BSZ 16
#define SEQ 4096
#define DIM 512

// ---------- complex helpers (float2 = {re, im}) ----------
__device__ __forceinline__ float2 cadd(float2 a, float2 b){ return make_float2(a.x+b.x, a.y+b.y); }
__device__ __forceinline__ float2 csub(float2 a, float2 b){ return make_float2(a.x-b.x, a.y-b.y); }
__device__ __forceinline__ float2 cmul(float2 a, float2 b){
  return make_float2(fmaf(a.x, b.x, -(a.y*b.y)), fmaf(a.x, b.y, a.y*b.x));
}
__device__ __forceinline__ float2 cmulc(float2 a, float2 b){ // a * conj(b)
  return make_float2(fmaf(a.x, b.x, a.y*b.y), fmaf(a.y, b.x, -(a.x*b.y)));
}
__device__ __forceinline__ float2 mul_mi(float2 a){ return make_float2(a.y, -a.x); } // a * (-i)

// 8-point DFT, natural in / natural out, W = exp(-2*pi*i/8)
__device__ __forceinline__ void dft8(const float2* in, float2* out){
  float2 t0 = cadd(in[0], in[4]), t1 = csub(in[0], in[4]);
  float2 t2 = cadd(in[2], in[6]), t3 = csub(in[2], in[6]);
  float2 E0 = cadd(t0, t2), E2 = csub(t0, t2);
  float2 m3 = mul_mi(t3);
  float2 E1 = cadd(t1, m3), E3 = csub(t1, m3);
  float2 s0 = cadd(in[1], in[5]), s1 = csub(in[1], in[5]);
  float2 s2 = cadd(in[3], in[7]), s3 = csub(in[3], in[7]);
  float2 O0 = cadd(s0, s2), O2 = csub(s0, s2);
  float2 n3 = mul_mi(s3);
  float2 O1 = cadd(s1, n3), O3 = csub(s1, n3);
  const float C = 0.70710678118654752440f;
  float2 w1o = make_float2(C*(O1.x + O1.y), C*(O1.y - O1.x));   // W8^1 * O1
  float2 w2o = mul_mi(O2);                                       // W8^2 * O2
  float2 w3o = make_float2(C*(O3.y - O3.x), -(C*(O3.x + O3.y))); // W8^3 * O3
  out[0] = cadd(E0, O0); out[4] = csub(E0, O0);
  out[1] = cadd(E1, w1o); out[5] = csub(E1, w1o);
  out[2] = cadd(E2, w2o); out[6] = csub(E2, w2o);
  out[3] = cadd(E3, w3o); out[7] = csub(E3, w3o);
}

// unscaled inverse 8-pt DFT: IDFT(a)[k] == DFT(a)[(-k) mod 8]
__device__ __forceinline__ void idft8(const float2* in, float2* out){
  float2 t[8];
  dft8(in, t);
  out[0]=t[0]; out[1]=t[7]; out[2]=t[6]; out[3]=t[5];
  out[4]=t[4]; out[5]=t[3]; out[6]=t[2]; out[7]=t[1];
}

// ---------- 512-pt FFT, one wave (64 lanes x 8 complex regs) ----------
// Forward (DIF radix-8): input natural order  v[j] = x[lane + 64*j];
// output digit-reversed: lane = 8*r + r2, reg m2 holds X[64*m2 + 8*r2 + r].
// LDS exchange addressing chosen so each b64 phase spans 16 distinct
// bank-pairs (conflict-free for 8B accesses):
//   exchange1: slot = 72*r + p        (p = position in 64-subseq)
//   exchange2: slot = r + 72*r2 + 8*i2
__device__ __forceinline__ void fft512_fwd(float2* v, float2* lds, int lane,
                                           const float2* wA, const float2* wB){
  const int r_hi = lane >> 3, r_lo = lane & 7;
  float2 t[8];
  // stage A: DFT8 across j (stride 64), twiddle W_512^(lane*r)
  dft8(v, t);
  #pragma unroll
  for (int r = 1; r < 8; ++r) t[r] = cmul(t[r], wA[r]);
  __syncthreads();
  #pragma unroll
  for (int r = 0; r < 8; ++r) lds[72*r + lane] = t[r];
  __syncthreads();
  #pragma unroll
  for (int j2 = 0; j2 < 8; ++j2) v[j2] = lds[72*r_hi + r_lo + 8*j2];
  // stage B: DFT8 across j2 (stride 8), twiddle W_64^(i2*r2), i2 = lane&7
  dft8(v, t);
  #pragma unroll
  for (int r2 = 1; r2 < 8; ++r2) t[r2] = cmul(t[r2], wB[r2]);
  __syncthreads();
  #pragma unroll
  for (int r2 = 0; r2 < 8; ++r2) lds[r_hi + 72*r2 + 8*r_lo] = t[r2];
  __syncthreads();
  #pragma unroll
  for (int i2 = 0; i2 < 8; ++i2) v[i2] = lds[r_hi + 72*r_lo + 8*i2];
  // stage C: final DFT8 (stride 1), no twiddle
  dft8(v, t);
  #pragma unroll
  for (int m = 0; m < 8; ++m) v[m] = t[m];
}

// Inverse (DIT radix-8): consumes digit-reversed layout, produces natural
// order v[j] = 512 * x[lane + 64*j] (scale 1/512 folded into p-spectrum).
__device__ __forceinline__ void fft512_inv(float2* v, float2* lds, int lane,
                                           const float2* wA, const float2* wB){
  const int r_hi = lane >> 3, r_lo = lane & 7;
  float2 t[8];
  // inverse of stage C
  idft8(v, t);
  __syncthreads();
  #pragma unroll
  for (int i2 = 0; i2 < 8; ++i2) lds[r_hi + 72*r_lo + 8*i2] = t[i2];
  __syncthreads();
  #pragma unroll
  for (int r2 = 0; r2 < 8; ++r2) v[r2] = lds[r_hi + 72*r2 + 8*r_lo];
  // inverse of stage B: conj twiddle first, then IDFT8
  #pragma unroll
  for (int r2 = 1; r2 < 8; ++r2) v[r2] = cmulc(v[r2], wB[r2]);
  idft8(v, t);
  __syncthreads();
  #pragma unroll
  for (int j2 = 0; j2 < 8; ++j2) lds[72*r_hi + r_lo + 8*j2] = t[j2];
  __syncthreads();
  #pragma unroll
  for (int r = 0; r < 8; ++r) v[r] = lds[72*r + lane];
  // inverse of stage A
  #pragma unroll
  for (int r = 1; r < 8; ++r) v[r] = cmulc(v[r], wA[r]);
  idft8(v, t);
  #pragma unroll
  for (int j = 0; j < 8; ++j) v[j] = t[j];
}

// One block (= one wave) per sequence position s.
// 1) compute P = fft(p[s]) / 512 once, keep in registers
// 2) for b = 0,2,..,14: z = x[b] + i*x[b+1]; y = ifft(fft(z) * P);
//    out[b] = Re(y), out[b+1] = Im(y)   (conv with a real kernel is C-linear)
__global__ void __launch_bounds__(64)
circconv_kernel(const float* __restrict__ x, const float* __restrict__ p,
                float* __restrict__ out){
  __shared__ float2 lds[576];
  const int lane = threadIdx.x;
  const int s = blockIdx.x;
  const int r_lo = lane & 7;

  // lane-only twiddles, computed once
  float2 wA[8], wB[8];
  wA[0] = make_float2(1.f, 0.f); wB[0] = make_float2(1.f, 0.f);
  #pragma unroll
  for (int r = 1; r < 8; ++r){
    float sv, cv;
    sincosf(-2.0f*(float)M_PI*(float)(lane*r)*(1.0f/512.0f), &sv, &cv);
    wA[r] = make_float2(cv, sv);
    sincosf(-2.0f*(float)M_PI*(float)(r_lo*r)*(1.0f/64.0f), &sv, &cv);
    wB[r] = make_float2(cv, sv);
  }

  // P spectrum for this s (scaled by 1/512 so inverse needs no scale)
  float2 pf[8];
  {
    const float* prow = p + (size_t)s * DIM;
    #pragma unroll
    for (int j = 0; j < 8; ++j) pf[j] = make_float2(prow[lane + 64*j], 0.f);
    fft512_fwd(pf, lds, lane, wA, wB);
    #pragma unroll
    for (int m = 0; m < 8; ++m){ pf[m].x *= (1.0f/512.0f); pf[m].y *= (1.0f/512.0f); }
  }

  for (int b = 0; b < BSZ; b += 2){
    const size_t base0 = ((size_t)b       * SEQ + s) * DIM;
    const size_t base1 = ((size_t)(b + 1) * SEQ + s) * DIM;
    float2 v[8];
    #pragma unroll
    for (int j = 0; j < 8; ++j)
      v[j] = make_float2(x[base0 + lane + 64*j], x[base1 + lane + 64*j]);
    fft512_fwd(v, lds, lane, wA, wB);
    #pragma unroll
    for (int m = 0; m < 8; ++m) v[m] = cmul(v[m], pf[m]);
    fft512_inv(v, lds, lane, wA, wB);
    #pragma unroll
    for (int j = 0; j < 8; ++j){
      out[base0 + lane + 64*j] = v[j].x;
      out[base1 + lane + 64*j] = v[j].y;
    }
  }
}

extern "C" void kernel_launch(void* const* d_in, const int* in_sizes, int n_in,
                              void* d_out, int out_size, void* d_ws, size_t ws_size,
                              hipStream_t stream) {
  (void)in_sizes; (void)n_in; (void)d_ws; (void)ws_size; (void)out_size;
  const float* x  = (const float*)d_in[0];
  const float* p  = (const float*)d_in[1];
  float* o        = (float*)d_out;
  circconv_kernel<<<SEQ, 64, 0, stream>>>(x, p, o);
}

// Round 2
// 243.032 us; speedup vs baseline: 1.0035x; 1.0035x over previous
//
#include <hip/hip_runtime.h>
#include <math.h>

#ifndef M_PI
#define M_PI 3.14159265358979323846
#endif

#define BSZ 16
#define SEQ 4096
#define DIM 512

// per-wave LDS region: exchange1 needs <=568 slots, exchange2 <=652; pad to 656
#define REG_SZ 656

// ---------- complex helpers (float2 = {re, im}) ----------
__device__ __forceinline__ float2 cadd(float2 a, float2 b){ return make_float2(a.x+b.x, a.y+b.y); }
__device__ __forceinline__ float2 csub(float2 a, float2 b){ return make_float2(a.x-b.x, a.y-b.y); }
__device__ __forceinline__ float2 cmul(float2 a, float2 b){
  return make_float2(fmaf(a.x, b.x, -(a.y*b.y)), fmaf(a.x, b.y, a.y*b.x));
}
__device__ __forceinline__ float2 cmulc(float2 a, float2 b){ // a * conj(b)
  return make_float2(fmaf(a.x, b.x, a.y*b.y), fmaf(a.y, b.x, -(a.x*b.y)));
}
__device__ __forceinline__ float2 mul_mi(float2 a){ return make_float2(a.y, -a.x); } // a * (-i)

// 8-point DFT, natural in / natural out, W = exp(-2*pi*i/8)
__device__ __forceinline__ void dft8(const float2* in, float2* out){
  float2 t0 = cadd(in[0], in[4]), t1 = csub(in[0], in[4]);
  float2 t2 = cadd(in[2], in[6]), t3 = csub(in[2], in[6]);
  float2 E0 = cadd(t0, t2), E2 = csub(t0, t2);
  float2 m3 = mul_mi(t3);
  float2 E1 = cadd(t1, m3), E3 = csub(t1, m3);
  float2 s0 = cadd(in[1], in[5]), s1 = csub(in[1], in[5]);
  float2 s2 = cadd(in[3], in[7]), s3 = csub(in[3], in[7]);
  float2 O0 = cadd(s0, s2), O2 = csub(s0, s2);
  float2 n3 = mul_mi(s3);
  float2 O1 = cadd(s1, n3), O3 = csub(s1, n3);
  const float C = 0.70710678118654752440f;
  float2 w1o = make_float2(C*(O1.x + O1.y), C*(O1.y - O1.x));   // W8^1 * O1
  float2 w2o = mul_mi(O2);                                       // W8^2 * O2
  float2 w3o = make_float2(C*(O3.y - O3.x), -(C*(O3.x + O3.y))); // W8^3 * O3
  out[0] = cadd(E0, O0); out[4] = csub(E0, O0);
  out[1] = cadd(E1, w1o); out[5] = csub(E1, w1o);
  out[2] = cadd(E2, w2o); out[6] = csub(E2, w2o);
  out[3] = cadd(E3, w3o); out[7] = csub(E3, w3o);
}

// unscaled inverse 8-pt DFT: IDFT(a)[k] == DFT(a)[(-k) mod 8]
__device__ __forceinline__ void idft8(const float2* in, float2* out){
  float2 t[8];
  dft8(in, t);
  out[0]=t[0]; out[1]=t[7]; out[2]=t[6]; out[3]=t[5];
  out[4]=t[4]; out[5]=t[3]; out[6]=t[2]; out[7]=t[1];
}

// ---------- 512-pt FFT, one wave (64 lanes x 8 complex regs) ----------
// Exchange addressing (bank-pair = (idx mod 16) must be bijective over each
// aligned 16-lane phase for conflict-free 8B LDS access):
//   exchange1: write idx = 72*r + lane        -> pair (8r+lane)%16  bijective
//              read  idx = 72*a + b + 8*j2    -> pair (8a+b)%16     bijective
//   exchange2: f2(a,u,w) = a + 82*u + 10*w    (bijective: a+10w<=77<82)
//              write (u const): pair (a+10w)%16  -> {0,10,4,14,8,2,12,6}+bit  OK
//              read  (w const): pair (a+2u)%16   -> bijective                 OK
__device__ __forceinline__ void fft512_fwd(float2* v, float2* lds, int lane,
                                           const float2* wA, const float2* wB){
  const int a = lane >> 3, b = lane & 7;
  float2 t[8];
  // stage A: DFT8 across stride 64, twiddle W_512^(lane*r)
  dft8(v, t);
  #pragma unroll
  for (int r = 1; r < 8; ++r) t[r] = cmul(t[r], wA[r]);
  __syncthreads();
  #pragma unroll
  for (int r = 0; r < 8; ++r) lds[72*r + lane] = t[r];
  __syncthreads();
  #pragma unroll
  for (int j2 = 0; j2 < 8; ++j2) v[j2] = lds[72*a + b + 8*j2];
  // stage B: DFT8 across stride 8, twiddle W_64^(b*r2)
  dft8(v, t);
  #pragma unroll
  for (int r2 = 1; r2 < 8; ++r2) t[r2] = cmul(t[r2], wB[r2]);
  __syncthreads();
  #pragma unroll
  for (int r2 = 0; r2 < 8; ++r2) lds[a + 82*r2 + 10*b] = t[r2];
  __syncthreads();
  #pragma unroll
  for (int i2 = 0; i2 < 8; ++i2) v[i2] = lds[a + 82*b + 10*i2];
  // stage C: final DFT8 (stride 1), no twiddle
  dft8(v, t);
  #pragma unroll
  for (int m = 0; m < 8; ++m) v[m] = t[m];
}

// Inverse (DIT): consumes digit-reversed layout, produces natural order,
// scaled by 512 (1/512 folded into the p-spectrum).
__device__ __forceinline__ void fft512_inv(float2* v, float2* lds, int lane,
                                           const float2* wA, const float2* wB){
  const int a = lane >> 3, b = lane & 7;
  float2 t[8];
  // inverse of stage C
  idft8(v, t);
  __syncthreads();
  #pragma unroll
  for (int i2 = 0; i2 < 8; ++i2) lds[a + 82*b + 10*i2] = t[i2];
  __syncthreads();
  #pragma unroll
  for (int r2 = 0; r2 < 8; ++r2) v[r2] = lds[a + 82*r2 + 10*b];
  // inverse of stage B
  #pragma unroll
  for (int r2 = 1; r2 < 8; ++r2) v[r2] = cmulc(v[r2], wB[r2]);
  idft8(v, t);
  __syncthreads();
  #pragma unroll
  for (int j2 = 0; j2 < 8; ++j2) lds[72*a + b + 8*j2] = t[j2];
  __syncthreads();
  #pragma unroll
  for (int r = 0; r < 8; ++r) v[r] = lds[72*r + lane];
  // inverse of stage A
  #pragma unroll
  for (int r = 1; r < 8; ++r) v[r] = cmulc(v[r], wA[r]);
  idft8(v, t);
  #pragma unroll
  for (int j = 0; j < 8; ++j) v[j] = t[j];
}

// 256-thread blocks = 4 waves; each wave independently handles one
// (s, batch-half) pair: 1 p-FFT + 4 complex-packed conv FFT round trips.
// Grid = SEQ*2/4 = 2048 blocks -> 8192 waves, ~24 waves/CU resident.
__global__ void __launch_bounds__(256)
circconv_kernel(const float* __restrict__ x, const float* __restrict__ p,
                float* __restrict__ out){
  __shared__ float2 lds_all[4 * REG_SZ];
  const int lane = threadIdx.x & 63;
  const int wid  = threadIdx.x >> 6;
  float2* lds = lds_all + wid * REG_SZ;

  const int g    = blockIdx.x * 4 + wid;   // global wave index
  const int s    = g >> 1;                  // sequence position
  const int half = g & 1;                   // batch half: rows 0-7 or 8-15
  const int b    = lane & 7;

  // lane-only twiddles, computed once
  float2 wA[8], wB[8];
  wA[0] = make_float2(1.f, 0.f); wB[0] = make_float2(1.f, 0.f);
  #pragma unroll
  for (int r = 1; r < 8; ++r){
    float sv, cv;
    sincosf(-2.0f*(float)M_PI*(float)(lane*r)*(1.0f/512.0f), &sv, &cv);
    wA[r] = make_float2(cv, sv);
    sincosf(-2.0f*(float)M_PI*(float)(b*r)*(1.0f/64.0f), &sv, &cv);
    wB[r] = make_float2(cv, sv);
  }

  // P spectrum for this s (scaled by 1/512 so inverse needs no scale)
  float2 pf[8];
  {
    const float* prow = p + (size_t)s * DIM;
    #pragma unroll
    for (int j = 0; j < 8; ++j) pf[j] = make_float2(prow[lane + 64*j], 0.f);
    fft512_fwd(pf, lds, lane, wA, wB);
    #pragma unroll
    for (int m = 0; m < 8; ++m){ pf[m].x *= (1.0f/512.0f); pf[m].y *= (1.0f/512.0f); }
  }

  // conv with a real kernel is C-linear: pack rows (bb, bb+1) as re/im
  const int b_lo = half * 8;
  for (int bb = b_lo; bb < b_lo + 8; bb += 2){
    const size_t base0 = ((size_t)bb       * SEQ + s) * DIM;
    const size_t base1 = ((size_t)(bb + 1) * SEQ + s) * DIM;
    float2 v[8];
    #pragma unroll
    for (int j = 0; j < 8; ++j)
      v[j] = make_float2(x[base0 + lane + 64*j], x[base1 + lane + 64*j]);
    fft512_fwd(v, lds, lane, wA, wB);
    #pragma unroll
    for (int m = 0; m < 8; ++m) v[m] = cmul(v[m], pf[m]);
    fft512_inv(v, lds, lane, wA, wB);
    #pragma unroll
    for (int j = 0; j < 8; ++j){
      out[base0 + lane + 64*j] = v[j].x;
      out[base1 + lane + 64*j] = v[j].y;
    }
  }
}

extern "C" void kernel_launch(void* const* d_in, const int* in_sizes, int n_in,
                              void* d_out, int out_size, void* d_ws, size_t ws_size,
                              hipStream_t stream) {
  (void)in_sizes; (void)n_in; (void)d_ws; (void)ws_size; (void)out_size;
  const float* x  = (const float*)d_in[0];
  const float* p  = (const float*)d_in[1];
  float* o        = (float*)d_out;
  circconv_kernel<<<SEQ*2/4, 256, 0, stream>>>(x, p, o);
}